// Round 1
// baseline (236.956 us; speedup 1.0000x reference)
//
#include <hip/hip_runtime.h>
#include <hip/hip_bf16.h>

using bf16 = __hip_bfloat16;
typedef __attribute__((ext_vector_type(8))) short bf16x8;
typedef __attribute__((ext_vector_type(4))) float f32x4;

#define NB   1024
#define TT   14
#define DM   1024
#define ROWS (NB*TT)   // 14336
#define NCAT 1280      // 1216 padded to 10*128

__device__ __forceinline__ unsigned short f2b(float f) {
  union { bf16 h; unsigned short u; } cv; cv.h = __float2bfloat16(f); return cv.u;
}

// ---------------- fp32 -> bf16 straight convert (vectorized) ----------------
__global__ __launch_bounds__(256) void k_conv_bf16(const float* __restrict__ in,
                                                   bf16* __restrict__ out, int n4) {
  int idx = blockIdx.x * 256 + threadIdx.x;
  int stride = gridDim.x * 256;
  for (int i = idx; i < n4; i += stride) {
    float4 v = reinterpret_cast<const float4*>(in)[i];
    ushort4 o;
    o.x = f2b(v.x); o.y = f2b(v.y); o.z = f2b(v.z); o.w = f2b(v.w);
    reinterpret_cast<ushort4*>(out)[i] = o;
  }
}

// ------------- fp32 [K=1024][Nin] -> bf16 transposed [Nin][1024] ------------
__global__ __launch_bounds__(256) void k_transpose(const float* __restrict__ in,
                                                   bf16* __restrict__ out, int Nin) {
  __shared__ float t[32][33];
  int k0 = blockIdx.x * 32, n0 = blockIdx.y * 32;
  int lx = threadIdx.x & 31, ly = threadIdx.x >> 5;   // 32 x 8
#pragma unroll
  for (int r = 0; r < 32; r += 8) {
    int n = n0 + lx;
    t[ly + r][lx] = (n < Nin) ? in[(size_t)(k0 + ly + r) * Nin + n] : 0.0f;
  }
  __syncthreads();
#pragma unroll
  for (int r = 0; r < 32; r += 8) {
    int n = n0 + ly + r;
    if (n < Nin) out[(size_t)n * 1024 + (k0 + lx)] = __float2bfloat16(t[lx][ly + r]);
  }
}

__global__ __launch_bounds__(256) void k_zero_bf16(bf16* p, int n) {
  int i = blockIdx.x * 256 + threadIdx.x;
  if (i < n) reinterpret_cast<unsigned short*>(p)[i] = 0;
}

// ------------------------- concatenated bias [1280] -------------------------
__global__ __launch_bounds__(256) void k_bcat(const float* bv, const float* bo,
                                              const float* ba, float* out) {
  int i = blockIdx.x * 256 + threadIdx.x;
  if (i >= NCAT) return;
  float v = 0.0f;
  if (i < 1024) v = bv[i];
  else if (i < 1152) v = bo[i - 1024];
  else if (i < 1216) v = ba[i - 1152];
  out[i] = v;
}

// ---------------- b_comb[j] = sum_i b_out[i]*W_proj[i][j] + b_proj[j] -------
__global__ __launch_bounds__(256) void k_bcomb(const float* __restrict__ b_out,
                                               const float* __restrict__ W_proj,
                                               const float* __restrict__ b_proj,
                                               float* __restrict__ out) {
  int j = blockIdx.x * 256 + threadIdx.x;   // 1024 threads
  float acc = b_proj[j];
  for (int i = 0; i < 1024; ++i) acc += b_out[i] * W_proj[(size_t)i * 1024 + j];
  out[j] = acc;
}

// --------------------------- bf16 MFMA GEMM (B^T) ---------------------------
// C[m][n] = sum_k A[m][k] * Bt[n][k]  (+ bias[n]).  M%128==0, N%128==0, K%32==0.
template<int OUT_BF16, int HAS_BIAS>
__global__ __launch_bounds__(256, 2) void k_gemm_bt(const bf16* __restrict__ A,
                                                    const bf16* __restrict__ Bt,
                                                    void* __restrict__ Cv,
                                                    const float* __restrict__ bias,
                                                    int M, int N, int K) {
  __shared__ bf16 As[128 * 32];
  __shared__ bf16 Bs[128 * 32];
  const int tid  = threadIdx.x;
  const int wave = tid >> 6, lane = tid & 63;
  const int row0 = blockIdx.y * 128, col0 = blockIdx.x * 128;
  const int wr = (wave >> 1) * 64, wc = (wave & 1) * 64;
  f32x4 acc[4][4] = {};

  const int sr = tid >> 2;          // staging row 0..63
  const int sc = (tid & 3) * 8;     // staging k offset (elements)
  const bf16* Ab  = A  + (size_t)(row0 + sr) * K + sc;
  const bf16* Ab2 = Ab + (size_t)64 * K;
  const bf16* Bb  = Bt + (size_t)(col0 + sr) * K + sc;
  const bf16* Bb2 = Bb + (size_t)64 * K;
  bf16* AsD  = As + tid * 8;
  bf16* AsD2 = As + tid * 8 + 2048;
  bf16* BsD  = Bs + tid * 8;
  bf16* BsD2 = Bs + tid * 8 + 2048;

  const int fr = lane & 15;
  const int kb = (lane >> 4) * 8;
  const int nk = K >> 5;

  for (int kk = 0; kk < nk; ++kk) {
    __syncthreads();
    const int ko = kk * 32;
    __builtin_amdgcn_global_load_lds((const __attribute__((address_space(1))) void*)(Ab  + ko),
                                     (__attribute__((address_space(3))) void*)AsD,  16, 0, 0);
    __builtin_amdgcn_global_load_lds((const __attribute__((address_space(1))) void*)(Ab2 + ko),
                                     (__attribute__((address_space(3))) void*)AsD2, 16, 0, 0);
    __builtin_amdgcn_global_load_lds((const __attribute__((address_space(1))) void*)(Bb  + ko),
                                     (__attribute__((address_space(3))) void*)BsD,  16, 0, 0);
    __builtin_amdgcn_global_load_lds((const __attribute__((address_space(1))) void*)(Bb2 + ko),
                                     (__attribute__((address_space(3))) void*)BsD2, 16, 0, 0);
    asm volatile("s_waitcnt vmcnt(0)" ::: "memory");
    __syncthreads();

    bf16x8 af[4], bfr[4];
#pragma unroll
    for (int mi = 0; mi < 4; ++mi)
      af[mi] = *(const bf16x8*)(As + (wr + mi * 16 + fr) * 32 + kb);
#pragma unroll
    for (int ni = 0; ni < 4; ++ni)
      bfr[ni] = *(const bf16x8*)(Bs + (wc + ni * 16 + fr) * 32 + kb);
#pragma unroll
    for (int mi = 0; mi < 4; ++mi)
#pragma unroll
      for (int ni = 0; ni < 4; ++ni)
        acc[mi][ni] = __builtin_amdgcn_mfma_f32_16x16x32_bf16(af[mi], bfr[ni], acc[mi][ni], 0, 0, 0);
  }

  const int fq = (lane >> 4) * 4;
#pragma unroll
  for (int mi = 0; mi < 4; ++mi) {
#pragma unroll
    for (int ni = 0; ni < 4; ++ni) {
      int gr = row0 + wr + mi * 16 + fq;
      int gc = col0 + wc + ni * 16 + fr;
      float bv = HAS_BIAS ? bias[gc] : 0.0f;
#pragma unroll
      for (int r = 0; r < 4; ++r) {
        float v = acc[mi][ni][r] + bv;
        if (OUT_BF16) ((bf16*)Cv)[(size_t)(gr + r) * N + gc] = __float2bfloat16(v);
        else          ((float*)Cv)[(size_t)(gr + r) * N + gc] = v;
      }
    }
  }
}

// ------------------------------- sampling -----------------------------------
// C1: [ROWS][1280] bf16 = [value(1024) | off(128) | attn(64) | pad(64)] (+bias).
// One wave per (b,t) row. Lane l owns (h,p)=(l>>2,l&3) weight computation;
// channel c = lane for the gather/accumulate.
__global__ __launch_bounds__(256) void k_sample(const bf16* __restrict__ C1,
                                                bf16* __restrict__ y) {
  const int wave = threadIdx.x >> 6, lane = threadIdx.x & 63;
  const int row = blockIdx.x * 4 + wave;           // < 14336
  const int b = row / TT, t = row - b * TT;
  const bf16* r1 = C1 + (size_t)row * NCAT;

  // ---- per-lane (h,p) weights ----
  float offx, offy;
  {
    ushort2 u = *reinterpret_cast<const ushort2*>(r1 + 1024 + lane * 2);
    offx = __uint_as_float(((unsigned)u.x) << 16);
    offy = __uint_as_float(((unsigned)u.y) << 16);
  }
  float logit;
  {
    unsigned short u = reinterpret_cast<const unsigned short*>(r1)[1152 + lane];
    logit = __uint_as_float(((unsigned)u) << 16);
  }
  // softmax over the 4 points (lanes grouped by p = lane&3)
  float m = fmaxf(logit, __shfl_xor(logit, 1));
  m = fmaxf(m, __shfl_xor(m, 2));
  float e = __expf(logit - m);
  float s = e + __shfl_xor(e, 1);
  s = s + __shfl_xor(s, 2);
  float aw = e / s;

  const float refx = (float)t * (1.0f / 13.0f);
  float ix = refx + offx - 0.5f;            // W_SP==1: loc_x*W - 0.5
  float xf = floorf(ix);
  float fx = ix - xf;
  float wx = (xf == 0.0f) ? (1.0f - fx) : ((xf == -1.0f) ? fx : 0.0f);

  float iy = offy - 0.5f;                   // (off_y/14)*14 - 0.5
  float yf = floorf(iy);
  float fy = iy - yf;
  int y0 = (int)yf, y1 = y0 + 1;
  float w0 = (y0 >= 0 && y0 < TT) ? (1.0f - fy) : 0.0f;
  float w1 = (y1 >= 0 && y1 < TT) ? fy : 0.0f;
  int i0 = max(0, min(TT - 1, y0));
  int i1 = max(0, min(TT - 1, y1));
  float cw0 = aw * wx * w0;
  float cw1 = aw * wx * w1;

  // ---- gather + accumulate: channel = lane, loop over 64 (h,p) pairs ----
  const bf16* vb = C1 + (size_t)(b * TT) * NCAT;   // value rows for this batch
  float acc[16];
#pragma unroll
  for (int h = 0; h < 16; ++h) acc[h] = 0.0f;
#pragma unroll
  for (int j = 0; j < 64; ++j) {
    float c0 = __shfl(cw0, j);
    float c1 = __shfl(cw1, j);
    int a0 = __shfl(i0, j);
    int a1 = __shfl(i1, j);
    const int hh = j >> 2;
    float v0 = __bfloat162float(vb[(size_t)a0 * NCAT + hh * 64 + lane]);
    float v1 = __bfloat162float(vb[(size_t)a1 * NCAT + hh * 64 + lane]);
    acc[hh] = fmaf(c0, v0, fmaf(c1, v1, acc[hh]));
  }
#pragma unroll
  for (int h = 0; h < 16; ++h)
    y[(size_t)row * DM + h * 64 + lane] = __float2bfloat16(acc[h]);
}

// ------------------------------- launcher -----------------------------------
extern "C" void kernel_launch(void* const* d_in, const int* in_sizes, int n_in,
                              void* d_out, int out_size, void* d_ws, size_t ws_size,
                              hipStream_t stream) {
  (void)in_sizes; (void)n_in; (void)out_size; (void)ws_size;
  const float* x       = (const float*)d_in[0];
  const float* W_value = (const float*)d_in[1];
  const float* b_value = (const float*)d_in[2];
  const float* W_off   = (const float*)d_in[3];
  const float* b_off   = (const float*)d_in[4];
  const float* W_attn  = (const float*)d_in[5];
  const float* b_attn  = (const float*)d_in[6];
  const float* W_out   = (const float*)d_in[7];
  const float* b_out   = (const float*)d_in[8];
  const float* W_proj  = (const float*)d_in[9];
  const float* b_proj  = (const float*)d_in[10];

  char* ws = (char*)d_ws;
  bf16*  x_bf    = (bf16*)(ws);                    // 29,360,128 B
  bf16*  y_bf    = x_bf;                           // alias (x dead after GEMM1)
  bf16*  C1      = (bf16*)(ws + 29360128);         // 36,700,160 B
  bf16*  Wcat_t  = (bf16*)(ws + 66060288);         //  2,621,440 B
  float* bcat    = (float*)(ws + 68681728);        //      5,120 B
  bf16*  Wout_b  = (bf16*)(ws + 68686848);         //  2,097,152 B
  bf16*  Wproj_t = (bf16*)(ws + 70784000);         //  2,097,152 B
  bf16*  Wc_t    = (bf16*)(ws + 72881152);         //  2,097,152 B
  float* bcomb   = (float*)(ws + 74978304);        //      4,096 B

  // -- conversions / small precomputes --
  k_conv_bf16<<<2048, 256, 0, stream>>>(x, x_bf, ROWS * DM / 4);
  k_transpose<<<dim3(32, 32), 256, 0, stream>>>(W_value, Wcat_t, 1024);
  k_transpose<<<dim3(32, 4),  256, 0, stream>>>(W_off,  Wcat_t + 1024 * 1024, 128);
  k_transpose<<<dim3(32, 2),  256, 0, stream>>>(W_attn, Wcat_t + 1152 * 1024, 64);
  k_zero_bf16<<<256, 256, 0, stream>>>(Wcat_t + 1216 * 1024, 64 * 1024);
  k_bcat<<<5, 256, 0, stream>>>(b_value, b_off, b_attn, bcat);
  k_conv_bf16<<<256, 256, 0, stream>>>(W_out, Wout_b, 1024 * 1024 / 4);
  k_transpose<<<dim3(32, 32), 256, 0, stream>>>(W_proj, Wproj_t, 1024);
  k_bcomb<<<4, 256, 0, stream>>>(b_out, W_proj, b_proj, bcomb);

  // -- fused projection GEMM: [14336,1024] x [1024,1280]^T -> C1 (bf16) --
  k_gemm_bt<1, 1><<<dim3(NCAT / 128, ROWS / 128), 256, 0, stream>>>(
      x_bf, Wcat_t, C1, bcat, ROWS, NCAT, DM);

  // -- W_comb^T = (W_out @ W_proj)^T via C[m][n] = sum_k Wproj[k][m]*Wout[n][k] --
  k_gemm_bt<1, 0><<<dim3(8, 8), 256, 0, stream>>>(
      Wproj_t, Wout_b, Wc_t, nullptr, 1024, 1024, 1024);

  // -- deformable sampling + head combine -> y (bf16) --
  k_sample<<<ROWS / 4, 256, 0, stream>>>(C1, y_bf);

  // -- final GEMM: y @ W_comb + b_comb -> out (fp32) --
  k_gemm_bt<0, 1><<<dim3(DM / 128, ROWS / 128), 256, 0, stream>>>(
      y_bf, Wc_t, (float*)d_out, bcomb, ROWS, DM, DM);
}

// Round 2
// 195.420 us; speedup vs baseline: 1.2125x; 1.2125x over previous
//
#include <hip/hip_runtime.h>
#include <hip/hip_bf16.h>

using bf16 = __hip_bfloat16;
typedef __attribute__((ext_vector_type(8))) short bf16x8;
typedef __attribute__((ext_vector_type(4))) float f32x4;

#define NB   1024
#define TT   14
#define DM   1024
#define ROWS (NB*TT)   // 14336
#define NCAT 1280      // 1216 padded to 10*128

__device__ __forceinline__ unsigned short f2b(float f) {
  union { bf16 h; unsigned short u; } cv; cv.h = __float2bfloat16(f); return cv.u;
}

__device__ __forceinline__ void gload16(const bf16* g, bf16* l) {
  __builtin_amdgcn_global_load_lds((const __attribute__((address_space(1))) void*)g,
                                   (__attribute__((address_space(3))) void*)l, 16, 0, 0);
}

// ---------------- fp32 -> bf16 straight convert (vectorized) ----------------
__global__ __launch_bounds__(256) void k_conv_bf16(const float* __restrict__ in,
                                                   bf16* __restrict__ out, int n4) {
  int idx = blockIdx.x * 256 + threadIdx.x;
  int stride = gridDim.x * 256;
  for (int i = idx; i < n4; i += stride) {
    float4 v = reinterpret_cast<const float4*>(in)[i];
    ushort4 o;
    o.x = f2b(v.x); o.y = f2b(v.y); o.z = f2b(v.z); o.w = f2b(v.w);
    reinterpret_cast<ushort4*>(out)[i] = o;
  }
}

// ------------- fp32 [1024][Nin] -> bf16 transposed [Nin][1024] --------------
__global__ __launch_bounds__(256) void k_transpose(const float* __restrict__ in,
                                                   bf16* __restrict__ out, int Nin) {
  __shared__ float t[32][33];
  int k0 = blockIdx.x * 32, n0 = blockIdx.y * 32;
  int lx = threadIdx.x & 31, ly = threadIdx.x >> 5;   // 32 x 8
#pragma unroll
  for (int r = 0; r < 32; r += 8)
    t[ly + r][lx] = in[(size_t)(k0 + ly + r) * Nin + (n0 + lx)];
  __syncthreads();
#pragma unroll
  for (int r = 0; r < 32; r += 8)
    out[(size_t)(n0 + ly + r) * 1024 + (k0 + lx)] = __float2bfloat16(t[lx][ly + r]);
}

// --- build Wcat_t [1280][1024] bf16 = [W_value|W_off|W_attn|0]^T, one pass ---
__global__ __launch_bounds__(256) void k_prep_wcat(const float* __restrict__ Wv,
                                                   const float* __restrict__ Wo,
                                                   const float* __restrict__ Wa,
                                                   bf16* __restrict__ out) {
  __shared__ float t[32][33];
  int k0 = blockIdx.x * 32, n0 = blockIdx.y * 32;   // grid (32, 40)
  int lx = threadIdx.x & 31, ly = threadIdx.x >> 5;
  const float* src; int base, width;
  if (n0 < 1024)      { src = Wv; base = 0;    width = 1024; }
  else if (n0 < 1152) { src = Wo; base = 1024; width = 128;  }
  else if (n0 < 1216) { src = Wa; base = 1152; width = 64;   }
  else                { src = nullptr; base = 0; width = 1;  }
#pragma unroll
  for (int r = 0; r < 32; r += 8)
    t[ly + r][lx] = src ? src[(size_t)(k0 + ly + r) * width + (n0 - base + lx)] : 0.0f;
  __syncthreads();
#pragma unroll
  for (int r = 0; r < 32; r += 8)
    out[(size_t)(n0 + ly + r) * 1024 + (k0 + lx)] = __float2bfloat16(t[lx][ly + r]);
}

// ------------------------- concatenated bias [1280] -------------------------
__global__ __launch_bounds__(256) void k_bcat(const float* bv, const float* bo,
                                              const float* ba, float* out) {
  int i = blockIdx.x * 256 + threadIdx.x;
  if (i >= NCAT) return;
  float v = 0.0f;
  if (i < 1024) v = bv[i];
  else if (i < 1152) v = bo[i - 1024];
  else if (i < 1216) v = ba[i - 1152];
  out[i] = v;
}

// ------- b_comb[j] = sum_i b_out[i]*W_proj[i][j] + b_proj[j]  (16 blocks) ----
__global__ __launch_bounds__(256) void k_bcomb(const float* __restrict__ b_out,
                                               const float* __restrict__ W_proj,
                                               const float* __restrict__ b_proj,
                                               float* __restrict__ out) {
  __shared__ float part[4][64];
  int j0 = blockIdx.x * 64;
  int jl = threadIdx.x & 63, ip = threadIdx.x >> 6;
  int j = j0 + jl;
  float acc = 0.0f;
  int i0 = ip * 256;
  for (int i = i0; i < i0 + 256; ++i)
    acc = fmaf(b_out[i], W_proj[(size_t)i * 1024 + j], acc);
  part[ip][jl] = acc;
  __syncthreads();
  if (threadIdx.x < 64) {
    int jj = j0 + threadIdx.x;
    out[jj] = part[0][threadIdx.x] + part[1][threadIdx.x] +
              part[2][threadIdx.x] + part[3][threadIdx.x] + b_proj[jj];
  }
}

// --------------------------- bf16 MFMA GEMM (B^T) ---------------------------
// C[m][n] = sum_k A[m][k] * Bt[n][k]  (+ bias[n]).  M%128==0, N%128==0, K%32==0.
// 2-phase double-buffered LDS (T3 minimum recipe) + bijective XCD swizzle (T1).
template<int OUT_BF16, int HAS_BIAS, int SWZ>
__global__ __launch_bounds__(256, 4) void k_gemm_bt(const bf16* __restrict__ A,
                                                    const bf16* __restrict__ Bt,
                                                    void* __restrict__ Cv,
                                                    const float* __restrict__ bias,
                                                    int M, int N, int K,
                                                    int lda, int ldb) {
  __shared__ bf16 As[2 * 4096];
  __shared__ bf16 Bs[2 * 4096];
  const int tid  = threadIdx.x;
  const int wave = tid >> 6, lane = tid & 63;

  int bid = blockIdx.y * gridDim.x + blockIdx.x;
  if (SWZ) {
    int nwg = gridDim.x * gridDim.y;
    int q = nwg >> 3, r = nwg & 7;
    int xcd = bid & 7, li = bid >> 3;
    bid = (xcd < r ? xcd * (q + 1) : r * (q + 1) + (xcd - r) * q) + li;
  }
  const int bx = bid % gridDim.x, by = bid / gridDim.x;
  const int row0 = by * 128, col0 = bx * 128;
  const int wr = (wave >> 1) * 64, wc = (wave & 1) * 64;
  f32x4 acc[4][4] = {};

  const int sr = tid >> 2;          // staging row 0..63
  const int sc = (tid & 3) * 8;     // staging k offset (elements)
  const bf16* Ab  = A  + (size_t)(row0 + sr) * lda + sc;
  const bf16* Ab2 = Ab + (size_t)64 * lda;
  const bf16* Bb  = Bt + (size_t)(col0 + sr) * ldb + sc;
  const bf16* Bb2 = Bb + (size_t)64 * ldb;

  const int fr = lane & 15;
  const int kb = (lane >> 4) * 8;
  const int nk = K >> 5;

  auto STAGE = [&](int buf, int kk) {
    const int ko = kk * 32;
    bf16* asd = As + buf * 4096 + tid * 8;
    bf16* bsd = Bs + buf * 4096 + tid * 8;
    gload16(Ab  + ko, asd);
    gload16(Ab2 + ko, asd + 2048);
    gload16(Bb  + ko, bsd);
    gload16(Bb2 + ko, bsd + 2048);
  };
  auto COMPUTE = [&](int buf) {
    const bf16* as = As + buf * 4096;
    const bf16* bs = Bs + buf * 4096;
    bf16x8 af[4], bfr[4];
#pragma unroll
    for (int mi = 0; mi < 4; ++mi)
      af[mi] = *(const bf16x8*)(as + (wr + mi * 16 + fr) * 32 + kb);
#pragma unroll
    for (int ni = 0; ni < 4; ++ni)
      bfr[ni] = *(const bf16x8*)(bs + (wc + ni * 16 + fr) * 32 + kb);
#pragma unroll
    for (int mi = 0; mi < 4; ++mi)
#pragma unroll
      for (int ni = 0; ni < 4; ++ni)
        acc[mi][ni] = __builtin_amdgcn_mfma_f32_16x16x32_bf16(af[mi], bfr[ni], acc[mi][ni], 0, 0, 0);
  };

  // prologue
  STAGE(0, 0);
  asm volatile("s_waitcnt vmcnt(0)" ::: "memory");
  __syncthreads();
  int cur = 0;
  for (int kk = 1; kk < nk; ++kk) {
    STAGE(cur ^ 1, kk);           // async loads into the other buffer
    COMPUTE(cur);                 // overlap: MFMA + ds_read hide load latency
    asm volatile("s_waitcnt vmcnt(0)" ::: "memory");
    __syncthreads();
    cur ^= 1;
  }
  COMPUTE(cur);

  const int fq = (lane >> 4) * 4;
#pragma unroll
  for (int mi = 0; mi < 4; ++mi) {
#pragma unroll
    for (int ni = 0; ni < 4; ++ni) {
      int gr = row0 + wr + mi * 16 + fq;
      int gc = col0 + wc + ni * 16 + fr;
      float bv = HAS_BIAS ? bias[gc] : 0.0f;
#pragma unroll
      for (int r = 0; r < 4; ++r) {
        float v = acc[mi][ni][r] + bv;
        if (OUT_BF16) ((bf16*)Cv)[(size_t)(gr + r) * N + gc] = __float2bfloat16(v);
        else          ((float*)Cv)[(size_t)(gr + r) * N + gc] = v;
      }
    }
  }
}

// ------------------------------- sampling -----------------------------------
// C1: [ROWS][1280] bf16 = [value(1024) | off(128) | attn(64) | pad(64)] (+bias).
// One wave per (b,t) row. Lane l owns (h,p)=(l>>2,l&3) weight computation;
// channel c = lane for the gather/accumulate.
__global__ __launch_bounds__(256) void k_sample(const bf16* __restrict__ C1,
                                                bf16* __restrict__ y) {
  const int wave = threadIdx.x >> 6, lane = threadIdx.x & 63;
  const int row = blockIdx.x * 4 + wave;           // < 14336
  const int b = row / TT, t = row - b * TT;
  const bf16* r1 = C1 + (size_t)row * NCAT;

  // ---- per-lane (h,p) weights ----
  float offx, offy;
  {
    ushort2 u = *reinterpret_cast<const ushort2*>(r1 + 1024 + lane * 2);
    offx = __uint_as_float(((unsigned)u.x) << 16);
    offy = __uint_as_float(((unsigned)u.y) << 16);
  }
  float logit;
  {
    unsigned short u = reinterpret_cast<const unsigned short*>(r1)[1152 + lane];
    logit = __uint_as_float(((unsigned)u) << 16);
  }
  // softmax over the 4 points (lanes grouped by p = lane&3)
  float m = fmaxf(logit, __shfl_xor(logit, 1));
  m = fmaxf(m, __shfl_xor(m, 2));
  float e = __expf(logit - m);
  float s = e + __shfl_xor(e, 1);
  s = s + __shfl_xor(s, 2);
  float aw = e / s;

  const float refx = (float)t * (1.0f / 13.0f);
  float ix = refx + offx - 0.5f;            // W_SP==1: loc_x*W - 0.5
  float xf = floorf(ix);
  float fx = ix - xf;
  float wx = (xf == 0.0f) ? (1.0f - fx) : ((xf == -1.0f) ? fx : 0.0f);

  float iy = offy - 0.5f;                   // (off_y/14)*14 - 0.5
  float yf = floorf(iy);
  float fy = iy - yf;
  int y0 = (int)yf, y1 = y0 + 1;
  float w0 = (y0 >= 0 && y0 < TT) ? (1.0f - fy) : 0.0f;
  float w1 = (y1 >= 0 && y1 < TT) ? fy : 0.0f;
  int i0 = max(0, min(TT - 1, y0));
  int i1 = max(0, min(TT - 1, y1));
  float cw0 = aw * wx * w0;
  float cw1 = aw * wx * w1;

  // ---- gather + accumulate: channel = lane, loop over 64 (h,p) pairs ----
  const bf16* vb = C1 + (size_t)(b * TT) * NCAT;   // value rows for this batch
  float acc[16];
#pragma unroll
  for (int h = 0; h < 16; ++h) acc[h] = 0.0f;
#pragma unroll
  for (int j = 0; j < 64; ++j) {
    float c0 = __shfl(cw0, j);
    float c1 = __shfl(cw1, j);
    int a0 = __shfl(i0, j);
    int a1 = __shfl(i1, j);
    const int hh = j >> 2;
    float v0 = __bfloat162float(vb[(size_t)a0 * NCAT + hh * 64 + lane]);
    float v1 = __bfloat162float(vb[(size_t)a1 * NCAT + hh * 64 + lane]);
    acc[hh] = fmaf(c0, v0, fmaf(c1, v1, acc[hh]));
  }
#pragma unroll
  for (int h = 0; h < 16; ++h)
    y[(size_t)row * DM + h * 64 + lane] = __float2bfloat16(acc[h]);
}

// ------------------------------- launcher -----------------------------------
extern "C" void kernel_launch(void* const* d_in, const int* in_sizes, int n_in,
                              void* d_out, int out_size, void* d_ws, size_t ws_size,
                              hipStream_t stream) {
  (void)in_sizes; (void)n_in; (void)out_size; (void)ws_size;
  const float* x       = (const float*)d_in[0];
  const float* W_value = (const float*)d_in[1];
  const float* b_value = (const float*)d_in[2];
  const float* W_off   = (const float*)d_in[3];
  const float* b_off   = (const float*)d_in[4];
  const float* W_attn  = (const float*)d_in[5];
  const float* b_attn  = (const float*)d_in[6];
  const float* W_out   = (const float*)d_in[7];
  const float* b_out   = (const float*)d_in[8];
  const float* W_proj  = (const float*)d_in[9];
  const float* b_proj  = (const float*)d_in[10];

  char* ws = (char*)d_ws;
  bf16*  x_bf    = (bf16*)(ws);                    // 29,360,128 B
  bf16*  y_bf    = x_bf;                           // alias (x dead after GEMM1)
  bf16*  C1      = (bf16*)(ws + 29360128);         // 36,700,160 B
  bf16*  Wcat_t  = (bf16*)(ws + 66060288);         //  2,621,440 B
  float* bcat    = (float*)(ws + 68681728);        //      5,120 B
  bf16*  Wout_b  = (bf16*)(ws + 68686848);         //  2,097,152 B
  bf16*  Wproj_t = (bf16*)(ws + 70784000);         //  2,097,152 B
  bf16*  Wc_t    = (bf16*)(ws + 72881152);         //  2,097,152 B
  float* bcomb   = (float*)(ws + 74978304);        //      4,096 B

  // -- conversions / small precomputes --
  k_conv_bf16<<<2048, 256, 0, stream>>>(x, x_bf, ROWS * DM / 4);
  k_prep_wcat<<<dim3(32, 40), 256, 0, stream>>>(W_value, W_off, W_attn, Wcat_t);
  k_bcat<<<5, 256, 0, stream>>>(b_value, b_off, b_attn, bcat);
  k_conv_bf16<<<256, 256, 0, stream>>>(W_out, Wout_b, 1024 * 1024 / 4);
  k_transpose<<<dim3(32, 32), 256, 0, stream>>>(W_proj, Wproj_t, 1024);
  k_bcomb<<<16, 256, 0, stream>>>(b_out, W_proj, b_proj, bcomb);

  // -- W_comb^T = (W_out @ W_proj)^T via C[m][n] = sum_k Wproj[k][m]*Wout[n][k] --
  k_gemm_bt<1, 0, 0><<<dim3(8, 8), 256, 0, stream>>>(
      Wproj_t, Wout_b, Wc_t, nullptr, 1024, 1024, 1024, 1024, 1024);

  // -- fused projection GEMM: [14336,1024] x [1024,1280]^T -> C1 (bf16) --
  k_gemm_bt<1, 1, 1><<<dim3(NCAT / 128, ROWS / 128), 256, 0, stream>>>(
      x_bf, Wcat_t, C1, bcat, ROWS, NCAT, DM, DM, DM);

  // -- deformable sampling + head combine -> y (bf16) --
  k_sample<<<ROWS / 4, 256, 0, stream>>>(C1, y_bf);

  // -- final GEMM: y @ W_comb + b_comb -> out (fp32) --
  k_gemm_bt<0, 1, 1><<<dim3(DM / 128, ROWS / 128), 256, 0, stream>>>(
      y_bf, Wc_t, (float*)d_out, bcomb, ROWS, DM, DM, DM, DM);
}